// Round 7
// baseline (111.457 us; speedup 1.0000x reference)
//
#include <hip/hip_runtime.h>

// Quanvolution: 8x1x128x128 input, K=3, STRIDE=2 -> 63x63 patches per image,
// 9-qubit statevector sim per patch, output (8, 9, 63, 63) PauliZ expvals.
//
// R22 = R21 with the launch-bounds residency cap lifted (the ONLY change).
// R21 (54.5us, best): VALU 66%, DS ~82%, Occupancy 47% == EXACTLY the
// (256,4) cap (4 waves/EU = 16/CU = 50%). The cap was a defensive R19
// leftover; kernel is 40 VGPR, so (256,8) costs the allocator nothing and
// doubles allowed residency -> fills the ~24k cyc/CU where both pipes idle
// on uncovered latency. Predicted: occupancy 65-85%, 45-49us (DS floor
// ~107k cyc = 45us). [R16's 6->8 lift was a no-op because its measured
// occupancy sat BELOW the cap; R21 is pressed AGAINST it.]
//
// Carried from R21 (verified, absmax 0.001953125):
//  - 2 patches/wave layout: amp bits [3:0]=reg slot (16 h2), [8:4]=lane5;
//    lanes 0-31 patch A, 32-63 patch B. DS/patch ~160 vs R16's 202.
//  - dtab [d][r][lane5]{cc,ns} coalesced layout + depth-1 reg prefetch
//    (D_A before build, D_B before ring1+Y1, D_C before ring2+Y0).
//  - ring1/ring2 pull-backs, deferred-CNOT Y swaps, 5-stage WHT
//    measurement, gather via wmask>>4 lanes (all HW-verified R19/R20).

namespace {

constexpr int OUT_HW = 63;
constexpr int N_PIX = OUT_HW * OUT_HW;                  // 3969
constexpr int PPB = 4;                                  // waves per block
constexpr int N_PATCH_TOTAL = 8 * N_PIX;                // 31752 == 3969*4*2

typedef _Float16 h2 __attribute__((ext_vector_type(2)));
typedef __fp16  hw2 __attribute__((ext_vector_type(2)));

__device__ __forceinline__ int h2i(h2 v) { return __builtin_bit_cast(int, v); }
__device__ __forceinline__ h2  i2h(int v) { return __builtin_bit_cast(h2, v); }
__device__ __forceinline__ h2  swap_h2(h2 v) { return __builtin_shufflevector(v, v, 1, 0); }

__device__ __forceinline__ int bperm_i(int addr, int v) {
    return __builtin_amdgcn_ds_bpermute(addr, v);
}

// xor-shuffle: ds_swizzle for mask<32 (stays within 32-lane groups, so
// patch halves never mix), ds_bpermute fallback for 32 (unused here).
template<int M>
__device__ __forceinline__ int shfl_i(int v, int lane) {
    if constexpr (M < 32)
        return __builtin_amdgcn_ds_swizzle(v, 0x1F | (M << 10));
    else
        return bperm_i((lane << 2) ^ 128, v);
}
template<int M>
__device__ __forceinline__ float shfl_f(float v, int lane) {
    return __int_as_float(shfl_i<M>(__float_as_int(v), lane));
}

// Reg-reg CNOT renames over 16 regs.
template<int C, int T>
__device__ __forceinline__ void cnot16(h2 (&a)[16])
{
    constexpr int cm = 1 << C, tm = 1 << T;
    #pragma unroll
    for (int r = 0; r < 16; ++r) {
        if ((r & cm) && !(r & tm)) {
            const int r1 = r | tm;
            const h2 t = a[r]; a[r] = a[r1]; a[r1] = t;
        }
    }
}

// Ring r=1 minus trailing cnot(8,0): renames (0,1)(1,2)(2,3);
// lane chain (3,4)..(7,8) pull-back: src_l5 = l5 ^ ((l5&15)<<1) ^ bit3(r).
__device__ __forceinline__ void ring1_partial16(h2 (&a)[16], int lane)
{
    cnot16<0,1>(a);
    cnot16<1,2>(a);
    cnot16<2,3>(a);
    const int l5 = lane & 31;
    const int hi = (lane & 32) << 2;
    const int sA = ((l5 ^ ((l5 & 15) << 1)) << 2) | hi;
    const int sB = sA ^ 4;                       // ^= bit3(reg) on lane bit0
    #pragma unroll
    for (int r = 0; r < 16; ++r)
        a[r] = i2h(bperm_i((r & 8) ? sB : sA, h2i(a[r])));
}

// Ring r=2 minus trailing (7,0),(8,1): renames (0,2)(1,3);
// chain (2,4)..(6,8) pull-back: src_l5 = l5 ^ ((l5&7)<<2) ^ (r3<<1) ^ r2.
__device__ __forceinline__ void ring2_partial16(h2 (&a)[16], int lane)
{
    cnot16<0,2>(a);
    cnot16<1,3>(a);
    const int l5 = lane & 31;
    const int s0 = ((l5 ^ ((l5 & 7) << 2)) << 2) | ((lane & 32) << 2);
    #pragma unroll
    for (int r = 0; r < 16; ++r) {
        const int ad = s0 ^ (((r >> 3) & 1) << 3) ^ (((r >> 2) & 1) << 2);
        a[r] = i2h(bperm_i(ad, h2i(a[r])));
    }
}

// Prefetch one diag cluster into registers (32 VGPRs).
// dtab layout: [d][r][lane5] pairs -> load at (dbase + r*32 + lane5)*2 is
// lane-stride-8B COALESCED (256B per half; halves read identical addrs).
__device__ __forceinline__ void load_diag16(h2 (&cc)[16], h2 (&ns)[16],
                                            const int* __restrict__ dtab,
                                            int dbase, int lane5)
{
    #pragma unroll
    for (int r = 0; r < 16; ++r) {
        const int idx = (dbase + r * 32 + lane5) * 2;
        cc[r] = i2h(dtab[idx]);
        ns[r] = i2h(dtab[idx + 1]);
    }
}

// Apply a prefetched diag cluster.
__device__ __forceinline__ void apply_diag16_pre(h2 (&a)[16],
                                                 const h2 (&cc)[16],
                                                 const h2 (&ns)[16])
{
    #pragma unroll
    for (int r = 0; r < 16; ++r)
        a[r] = cc[r] * a[r] + ns[r] * swap_h2(a[r]);
}

// RY on reg qubit QM.
template<int QM>
__device__ __forceinline__ void regY16(h2 (&a)[16], h2 A2, h2 B2, h2 C2, h2 D2)
{
    #pragma unroll
    for (int r = 0; r < 16; ++r) {
        if (!(r & QM)) {
            const int r1 = r | QM;
            const h2 x0 = a[r], x1 = a[r1];
            a[r]  = A2 * x0 + B2 * x1;
            a[r1] = C2 * x0 + D2 * x1;
        }
    }
}

// RY on lane qubit LM: out = c2*self + sp2*partner.
template<int LM>
__device__ __forceinline__ void laneY16(h2 (&a)[16], int lane, h2 c2, h2 sp2)
{
    #pragma unroll
    for (int r = 0; r < 16; ++r) {
        const h2 p = i2h(shfl_i<LM>(h2i(a[r]), lane));
        a[r] = c2 * a[r] + sp2 * p;
    }
}

// Full RY layer. yt: 9 gates x {cc,ss,nss}. regY q0..q3 (masks 1,2,4,8),
// laneY q4..q8 (masks 1,2,4,8,16). sw0/sw1: deferred-CNOT column swaps
// on q0/q1 (verified R5 mechanism, unchanged).
__device__ __forceinline__ void apply_Y16(h2 (&a)[16], int lane,
                                          const int* __restrict__ yt,
                                          bool sw0, bool sw1)
{
    {   const int cc = yt[0], ss = yt[1], ns = yt[2];
        regY16<1>(a, i2h(sw0 ? ns : cc), i2h(sw0 ? cc : ns),
                     i2h(sw0 ? cc : ss), i2h(sw0 ? ss : cc)); }
    {   const int cc = yt[3], ss = yt[4], ns = yt[5];
        regY16<2>(a, i2h(sw1 ? ns : cc), i2h(sw1 ? cc : ns),
                     i2h(sw1 ? cc : ss), i2h(sw1 ? ss : cc)); }
    {   regY16<4>(a, i2h(yt[6]),  i2h(yt[8]),  i2h(yt[7]),  i2h(yt[6])); }
    {   regY16<8>(a, i2h(yt[9]),  i2h(yt[11]), i2h(yt[10]), i2h(yt[9])); }
    {   laneY16<1> (a, lane, i2h(yt[12]), i2h((lane & 1)        ? yt[13] : yt[14])); }
    {   laneY16<2> (a, lane, i2h(yt[15]), i2h(((lane >> 1) & 1) ? yt[16] : yt[17])); }
    {   laneY16<4> (a, lane, i2h(yt[18]), i2h(((lane >> 2) & 1) ? yt[19] : yt[20])); }
    {   laneY16<8> (a, lane, i2h(yt[21]), i2h(((lane >> 3) & 1) ? yt[22] : yt[23])); }
    {   laneY16<16>(a, lane, i2h(yt[24]), i2h(((lane >> 4) & 1) ? yt[25] : yt[26])); }
}

// ---- Precompute (weights-only).
// ws layout (floats): [0..144) rot fp32; ints at ws+144: ytab 54 ints;
// ints at ws+208: dtab 3*512*2 ints, layout [d][r=amp&15][l5=amp>>4]{cc,ns}.
__global__ void precomp_kernel(const float* __restrict__ w, float* __restrict__ ws)
{
    const int tid = threadIdx.x;
    float* rot = ws;
    int* ytab = (int*)(ws + 144);
    int* dtab = (int*)(ws + 208);
    if (tid < 18) {
        const float phi = w[tid*3 + 0], theta = w[tid*3 + 1], omega = w[tid*3 + 2];
        const float ct = cosf(0.5f * theta), st = sinf(0.5f * theta);
        const float apo = 0.5f * (phi + omega), amo = 0.5f * (phi - omega);
        const float ca = cosf(apo), sa = sinf(apo);
        const float cm = cosf(amo), sm = sinf(amo);
        float* m = rot + tid * 8;
        m[0] =  ca * ct; m[1] = -sa * ct;   // u00
        m[2] = -cm * st; m[3] = -sm * st;   // u01
        m[4] =  cm * st; m[5] = -sm * st;   // u10
        m[6] =  ca * ct; m[7] =  sa * ct;   // u11
        h2 cc; cc.x = (_Float16)ct;  cc.y = (_Float16)ct;
        h2 ss; ss.x = (_Float16)st;  ss.y = (_Float16)st;
        h2 ns; ns.x = (_Float16)(-st); ns.y = (_Float16)(-st);
        ytab[tid*3 + 0] = h2i(cc);
        ytab[tid*3 + 1] = h2i(ss);
        ytab[tid*3 + 2] = h2i(ns);
    }
    if (tid < 192) {
        // ring1 pull-back masks (row-update rule; procedure verified vs ring2)
        const int vmask[9] = {0x1FE,0x003,0x007,0x00F,0x01F,0x03F,0x07F,0x0FF,0x1FF};
        // ring2 pull-back masks (HW-verified R4/R5)
        const int wmask[9] = {0x0AB,0x157,0x005,0x00A,0x015,0x02A,0x055,0x0AA,0x155};
        const int d = tid >> 6, ln = tid & 63;
        for (int r = 0; r < 8; ++r) {
            const int p = (ln << 3) | r;     // enumerates all 512 amp indices
            float ang = 0.f;
            for (int q = 0; q < 9; ++q) {
                if (d == 0) {            // D_A: conj(Phi_l1) through ring1
                    const float lam = -0.5f * w[(9 + q)*3 + 0];
                    ang += (__popc(p & vmask[q]) & 1) ? -lam : lam;
                } else if (d == 1) {     // D_B: conj(Phi_l0) thru ring2 + Omega_l1
                    const float lam = -0.5f * w[q*3 + 0];
                    ang += (__popc(p & wmask[q]) & 1) ? -lam : lam;
                    const float lm2 = -0.5f * w[(9 + q)*3 + 2];
                    ang += ((p >> q) & 1) ? -lm2 : lm2;
                } else {                 // D_C: conj(Phi_l1) thru ring1 + Omega_l0
                    const float lam = -0.5f * w[(9 + q)*3 + 0];
                    ang += (__popc(p & vmask[q]) & 1) ? -lam : lam;
                    const float lm2 = -0.5f * w[q*3 + 2];
                    ang += ((p >> q) & 1) ? -lm2 : lm2;
                }
            }
            const float c = cosf(ang), s = sinf(ang);
            h2 cc;  cc.x = (_Float16)c;    cc.y = (_Float16)c;
            h2 nsp; nsp.x = (_Float16)(-s); nsp.y = (_Float16)s;  // {-s,+s}
            // coalesced-read layout: [d][p&15][p>>4]
            const int idx = (d * 512 + (p & 15) * 32 + (p >> 4)) * 2;
            dtab[idx + 0] = h2i(cc);
            dtab[idx + 1] = h2i(nsp);
        }
    }
}

__global__ __launch_bounds__(PPB * 64, 8) void qconv_kernel(
    const float* __restrict__ x,      // (8, 1, 128, 128)
    const float* __restrict__ ws,     // precomp tables
    float* __restrict__ out)          // (8, 9, 63, 63)
{
    const float* rot  = ws;
    const int* ytab = (const int*)(ws + 144);
    const int* dtab = (const int*)(ws + 208);

    const int lane   = threadIdx.x & 63;
    const int wv     = threadIdx.x >> 6;
    const int lane5  = lane & 31;
    const int half   = lane >> 5;                       // 0: patch A, 1: patch B
    const int patch2 = (blockIdx.x * PPB + wv) * 2;     // wave's first patch

    // ---- Per-wave alpha/beta staging: 72 values (2 patches x 36).
    // Pass 1: lane -> value lane (patchA j=0..35 | patchB j=0..27);
    // pass 2: lanes 0-7 -> patchB j=28..35.
    __shared__ __align__(16) float abtab[PPB][2][36];
    {
        auto stage_val = [&](int h, int j) {
            const int q = j >> 2, comp = j & 3;
            const int tp   = patch2 + h;
            const int tb   = tp / N_PIX;
            const int trem = tp - tb * N_PIX;
            const int toy  = trem / OUT_HW;
            const int tox  = trem - toy * OUT_HW;
            const int qr = q / 3, qc = q - 3 * qr;
            const float ang = x[tb * 16384 + (toy * 2 + qr) * 128 + (tox * 2 + qc)];
            float s, c;
            __sincosf(0.5f * ang, &s, &c);
            const float* R = rot + 8 * q;
            float v;
            if      (comp == 0) v = c*R[0] + s*R[3];
            else if (comp == 1) v = c*R[1] - s*R[2];
            else if (comp == 2) v = c*R[4] + s*R[7];
            else                v = c*R[5] - s*R[6];
            abtab[wv][h][j] = v;
        };
        const int h1 = (lane >= 36) ? 1 : 0;
        stage_val(h1, lane - 36 * h1);
        if (lane < 8) stage_val(1, 28 + lane);
    }
    __builtin_amdgcn_wave_barrier();   // ordering fence; DS ops of one wave
                                       // execute in order (R17/R19-verified).

    // Each lane reads its half's 36 values: 9x ds_read_b128 (rows 144B,
    // 16B-aligned; two distinct addrs/wave broadcast within halves).
    float ab[36];
    {
        const float4* src = reinterpret_cast<const float4*>(&abtab[wv][half][0]);
        float4* dst = reinterpret_cast<float4*>(ab);
        #pragma unroll
        for (int j = 0; j < 9; ++j) dst[j] = src[j];
    }

    // D_A prefetch: issue before the product build (~150 VALU of cover).
    h2 dcc[16], dns[16];
    load_diag16(dcc, dns, dtab, 0 * 512, lane5);

    // ---- Product state: amp(p) = prod_q (bit_q(p) ? beta_q : alpha_q)
    // q0..q3 -> reg bits 0..3; q4..q8 -> lane5 bits 0..4.
    // NOTE: every ab[] access uses a COMPILE-TIME index; runtime selection
    // is done on values (v_cndmask), never inside the index (R19 spill bug).
    h2 a[16];
    {
        const int bit0 = lane5 & 1;              // q4 bit
        float Lr = bit0 ? ab[18] : ab[16];
        float Li = bit0 ? ab[19] : ab[17];
        #pragma unroll
        for (int q = 5; q <= 8; ++q) {
            const int bit = (lane5 >> (q - 4)) & 1;
            const float fr = bit ? ab[4*q + 2] : ab[4*q + 0];
            const float fi = bit ? ab[4*q + 3] : ab[4*q + 1];
            const float nr = Lr*fr - Li*fi;
            const float ni = Lr*fi + Li*fr;
            Lr = nr; Li = ni;
        }
        float c01r[4], c01i[4], c23r[4], c23i[4];
        #pragma unroll
        for (int j = 0; j < 4; ++j) {
            const float f0r = (j & 1) ? ab[2]  : ab[0];
            const float f0i = (j & 1) ? ab[3]  : ab[1];
            const float f1r = (j & 2) ? ab[6]  : ab[4];
            const float f1i = (j & 2) ? ab[7]  : ab[5];
            c01r[j] = f0r*f1r - f0i*f1i;
            c01i[j] = f0r*f1i + f0i*f1r;
            const float g2r = (j & 1) ? ab[10] : ab[8];
            const float g2i = (j & 1) ? ab[11] : ab[9];
            const float g3r = (j & 2) ? ab[14] : ab[12];
            const float g3i = (j & 2) ? ab[15] : ab[13];
            c23r[j] = g2r*g3r - g2i*g3i;
            c23i[j] = g2r*g3i + g2i*g3r;
        }
        float hlr[4], hli[4];
        #pragma unroll
        for (int j = 0; j < 4; ++j) {
            hlr[j] = c01r[j]*Lr - c01i[j]*Li;
            hli[j] = c01r[j]*Li + c01i[j]*Lr;
        }
        #pragma unroll
        for (int r = 0; r < 16; ++r) {
            const float fr = hlr[r & 3]*c23r[r >> 2] - hli[r & 3]*c23i[r >> 2];
            const float fi = hlr[r & 3]*c23i[r >> 2] + hli[r & 3]*c23r[r >> 2];
            a[r] = __builtin_bit_cast(h2, __builtin_amdgcn_cvt_pkrtz(fr, fi));
        }
    }

    const bool q7b = ((lane >> 3) & 1) != 0;    // amp bit 7 (qubit 7)
    const bool q8b = ((lane >> 4) & 1) != 0;    // amp bit 8 (qubit 8)

    // U = Y1 R1 D_C Y0 R2 D_B Y1 R1 D_A |build>, measured with ring2 masks.
    apply_diag16_pre(a, dcc, dns);                    // D_A
    load_diag16(dcc, dns, dtab, 1 * 512, lane5);      // D_B prefetch
    ring1_partial16(a, lane);                         // cnot(8,0) -> Y q0 swap
    apply_Y16(a, lane, ytab + 27, q8b, false);        // Y(l=1)
    apply_diag16_pre(a, dcc, dns);                    // D_B
    load_diag16(dcc, dns, dtab, 2 * 512, lane5);      // D_C prefetch
    ring2_partial16(a, lane);                         // (7,0),(8,1) -> Y q0/q1
    apply_Y16(a, lane, ytab + 0, q7b, q8b);           // Y(l=0)
    apply_diag16_pre(a, dcc, dns);                    // D_C
    ring1_partial16(a, lane);                         // cnot(8,0) -> Y q0 swap
    apply_Y16(a, lane, ytab + 27, q8b, false);        // Y(l=1)
    // final Omega(l=1) dropped; final ring2 absorbed into the Walsh masks.

    // ---- Measurement: e_q = sum_p (-1)^{parity(p & w_q)} |amp_p|^2
    float p[16];
    #pragma unroll
    for (int r = 0; r < 16; ++r) {
#if __has_builtin(__builtin_amdgcn_fdot2)
        p[r] = __builtin_amdgcn_fdot2(__builtin_bit_cast(hw2, a[r]),
                                      __builtin_bit_cast(hw2, a[r]), 0.0f, false);
#else
        const float xr = (float)a[r].x, xi = (float)a[r].y;
        p[r] = xr*xr + xi*xi;
#endif
    }

    // 4 signed register sums over reg masks {5,7,10,11} (= wmask & 15).
    float A[8], B[8];
    #pragma unroll
    for (int j = 0; j < 8; ++j) {
        A[j] = p[2*j] + p[2*j+1];
        B[j] = p[2*j] - p[2*j+1];
    }
    float P5[4], P7[4], P10[4];
    #pragma unroll
    for (int k = 0; k < 4; ++k) {
        P5[k]  = B[2*k] + B[2*k+1];
        P7[k]  = B[2*k] - B[2*k+1];
        P10[k] = A[2*k] - A[2*k+1];
    }
    float S5  = (P5[0]  - P5[1])  + (P5[2]  - P5[3]);
    float S7  = (P7[0]  - P7[1])  + (P7[2]  - P7[3]);
    float S11 = (P7[0]  + P7[1])  - (P7[2]  + P7[3]);
    float S10 = (P10[0] + P10[1]) - (P10[2] + P10[3]);

    // ---- 4 simultaneous 32-lane Walsh-Hadamard transforms (per half).
    const int sm0 = (lane & 1) << 31;
    const int sm1 = ((lane >> 1) & 1) << 31;
    const int sm2 = ((lane >> 2) & 1) << 31;
    const int sm3 = ((lane >> 3) & 1) << 31;
    const int sm4 = ((lane >> 4) & 1) << 31;
#define WHT_STAGE(M, SM) { \
    const float qa = shfl_f<M>(S5, lane),  qb = shfl_f<M>(S7, lane); \
    const float qc = shfl_f<M>(S10, lane), qd = shfl_f<M>(S11, lane); \
    S5  = qa + __int_as_float(__float_as_int(S5)  ^ (SM)); \
    S7  = qb + __int_as_float(__float_as_int(S7)  ^ (SM)); \
    S10 = qc + __int_as_float(__float_as_int(S10) ^ (SM)); \
    S11 = qd + __int_as_float(__float_as_int(S11) ^ (SM)); }
    WHT_STAGE(1,  sm0)
    WHT_STAGE(2,  sm1)
    WHT_STAGE(4,  sm2)
    WHT_STAGE(8,  sm3)
    WHT_STAGE(16, sm4)
#undef WHT_STAGE

    // ---- Gather (per half; lane5 positions = wmask >> 4):
    // S5: e2@0, e4@1, e6@5, e8@0x15 | S10: e3@0, e5@2, e7@0xA
    // S11: e0@0xA | S7: e1@0x15
    const int patch = patch2 + half;
    const int b   = patch / N_PIX;
    const int rem = patch - b * N_PIX;
    const int oy  = rem / OUT_HW;
    const int ox  = rem - oy * OUT_HW;
    const int base = b * 9;
    const int pix  = oy * OUT_HW + ox;

    if (lane5 == 0x00) {
        out[(base + 2) * N_PIX + pix] = S5;
        out[(base + 3) * N_PIX + pix] = S10;
    }
    if (lane5 == 0x01) out[(base + 4) * N_PIX + pix] = S5;
    if (lane5 == 0x02) out[(base + 5) * N_PIX + pix] = S10;
    if (lane5 == 0x05) out[(base + 6) * N_PIX + pix] = S5;
    if (lane5 == 0x0A) {
        out[(base + 7) * N_PIX + pix] = S10;
        out[(base + 0) * N_PIX + pix] = S11;
    }
    if (lane5 == 0x15) {
        out[(base + 8) * N_PIX + pix] = S5;
        out[(base + 1) * N_PIX + pix] = S7;
    }
}

} // anonymous namespace

extern "C" void kernel_launch(void* const* d_in, const int* in_sizes, int n_in,
                              void* d_out, int out_size, void* d_ws, size_t ws_size,
                              hipStream_t stream)
{
    const float* x = (const float*)d_in[0];   // (8,1,128,128) float32
    const float* w = (const float*)d_in[1];   // (2,9,3) float32
    float* ws = (float*)d_ws;                 // ~3.3k floats scratch
    float* out = (float*)d_out;               // (8,9,63,63) float32

    precomp_kernel<<<1, 256, 0, stream>>>(w, ws);
    qconv_kernel<<<N_PATCH_TOTAL / (PPB * 2), PPB * 64, 0, stream>>>(x, ws, out);
}

// Round 8
// 108.757 us; speedup vs baseline: 1.0248x; 1.0248x over previous
//
#include <hip/hip_runtime.h>

// Quanvolution: 8x1x128x128 input, K=3, STRIDE=2 -> 63x63 patches per image,
// 9-qubit statevector sim per patch, output (8, 9, 63, 63) PauliZ expvals.
//
// R23 = R22 with __launch_bounds__ (256,8) -> (256,6). The ONLY change.
// R22 post-mortem: occupancy 47->61.5% confirmed the R21 cap was binding,
// BUT the 8-waves/EU bound made the allocator spill dcc/dns to scratch
// (VGPR 40->32, FETCH 941->4014KB, WRITE 1984->8128KB) -- spill traffic
// ate the occupancy gain (55.1us flat). 6 waves/EU = 85-VGPR budget: the
// ~48-56 live regs (a[16]+dcc[16]+dns[16]+temps) fit spill-free, residency
// cap 24 waves/CU covers the measured ~20-wave demand.
//
// Carried from R21 (verified, absmax 0.001953125):
//  - 2 patches/wave layout: amp bits [3:0]=reg slot (16 h2), [8:4]=lane5;
//    lanes 0-31 patch A, 32-63 patch B. DS/patch ~160 vs R16's 202.
//  - dtab [d][r][lane5]{cc,ns} coalesced layout + depth-1 reg prefetch
//    (D_A before build, D_B before ring1+Y1, D_C before ring2+Y0).
//  - ring1/ring2 pull-backs, deferred-CNOT Y swaps, 5-stage WHT
//    measurement, gather via wmask>>4 lanes (all HW-verified R19/R20).

namespace {

constexpr int OUT_HW = 63;
constexpr int N_PIX = OUT_HW * OUT_HW;                  // 3969
constexpr int PPB = 4;                                  // waves per block
constexpr int N_PATCH_TOTAL = 8 * N_PIX;                // 31752 == 3969*4*2

typedef _Float16 h2 __attribute__((ext_vector_type(2)));
typedef __fp16  hw2 __attribute__((ext_vector_type(2)));

__device__ __forceinline__ int h2i(h2 v) { return __builtin_bit_cast(int, v); }
__device__ __forceinline__ h2  i2h(int v) { return __builtin_bit_cast(h2, v); }
__device__ __forceinline__ h2  swap_h2(h2 v) { return __builtin_shufflevector(v, v, 1, 0); }

__device__ __forceinline__ int bperm_i(int addr, int v) {
    return __builtin_amdgcn_ds_bpermute(addr, v);
}

// xor-shuffle: ds_swizzle for mask<32 (stays within 32-lane groups, so
// patch halves never mix), ds_bpermute fallback for 32 (unused here).
template<int M>
__device__ __forceinline__ int shfl_i(int v, int lane) {
    if constexpr (M < 32)
        return __builtin_amdgcn_ds_swizzle(v, 0x1F | (M << 10));
    else
        return bperm_i((lane << 2) ^ 128, v);
}
template<int M>
__device__ __forceinline__ float shfl_f(float v, int lane) {
    return __int_as_float(shfl_i<M>(__float_as_int(v), lane));
}

// Reg-reg CNOT renames over 16 regs.
template<int C, int T>
__device__ __forceinline__ void cnot16(h2 (&a)[16])
{
    constexpr int cm = 1 << C, tm = 1 << T;
    #pragma unroll
    for (int r = 0; r < 16; ++r) {
        if ((r & cm) && !(r & tm)) {
            const int r1 = r | tm;
            const h2 t = a[r]; a[r] = a[r1]; a[r1] = t;
        }
    }
}

// Ring r=1 minus trailing cnot(8,0): renames (0,1)(1,2)(2,3);
// lane chain (3,4)..(7,8) pull-back: src_l5 = l5 ^ ((l5&15)<<1) ^ bit3(r).
__device__ __forceinline__ void ring1_partial16(h2 (&a)[16], int lane)
{
    cnot16<0,1>(a);
    cnot16<1,2>(a);
    cnot16<2,3>(a);
    const int l5 = lane & 31;
    const int hi = (lane & 32) << 2;
    const int sA = ((l5 ^ ((l5 & 15) << 1)) << 2) | hi;
    const int sB = sA ^ 4;                       // ^= bit3(reg) on lane bit0
    #pragma unroll
    for (int r = 0; r < 16; ++r)
        a[r] = i2h(bperm_i((r & 8) ? sB : sA, h2i(a[r])));
}

// Ring r=2 minus trailing (7,0),(8,1): renames (0,2)(1,3);
// chain (2,4)..(6,8) pull-back: src_l5 = l5 ^ ((l5&7)<<2) ^ (r3<<1) ^ r2.
__device__ __forceinline__ void ring2_partial16(h2 (&a)[16], int lane)
{
    cnot16<0,2>(a);
    cnot16<1,3>(a);
    const int l5 = lane & 31;
    const int s0 = ((l5 ^ ((l5 & 7) << 2)) << 2) | ((lane & 32) << 2);
    #pragma unroll
    for (int r = 0; r < 16; ++r) {
        const int ad = s0 ^ (((r >> 3) & 1) << 3) ^ (((r >> 2) & 1) << 2);
        a[r] = i2h(bperm_i(ad, h2i(a[r])));
    }
}

// Prefetch one diag cluster into registers (32 VGPRs).
// dtab layout: [d][r][lane5] pairs -> load at (dbase + r*32 + lane5)*2 is
// lane-stride-8B COALESCED (256B per half; halves read identical addrs).
__device__ __forceinline__ void load_diag16(h2 (&cc)[16], h2 (&ns)[16],
                                            const int* __restrict__ dtab,
                                            int dbase, int lane5)
{
    #pragma unroll
    for (int r = 0; r < 16; ++r) {
        const int idx = (dbase + r * 32 + lane5) * 2;
        cc[r] = i2h(dtab[idx]);
        ns[r] = i2h(dtab[idx + 1]);
    }
}

// Apply a prefetched diag cluster.
__device__ __forceinline__ void apply_diag16_pre(h2 (&a)[16],
                                                 const h2 (&cc)[16],
                                                 const h2 (&ns)[16])
{
    #pragma unroll
    for (int r = 0; r < 16; ++r)
        a[r] = cc[r] * a[r] + ns[r] * swap_h2(a[r]);
}

// RY on reg qubit QM.
template<int QM>
__device__ __forceinline__ void regY16(h2 (&a)[16], h2 A2, h2 B2, h2 C2, h2 D2)
{
    #pragma unroll
    for (int r = 0; r < 16; ++r) {
        if (!(r & QM)) {
            const int r1 = r | QM;
            const h2 x0 = a[r], x1 = a[r1];
            a[r]  = A2 * x0 + B2 * x1;
            a[r1] = C2 * x0 + D2 * x1;
        }
    }
}

// RY on lane qubit LM: out = c2*self + sp2*partner.
template<int LM>
__device__ __forceinline__ void laneY16(h2 (&a)[16], int lane, h2 c2, h2 sp2)
{
    #pragma unroll
    for (int r = 0; r < 16; ++r) {
        const h2 p = i2h(shfl_i<LM>(h2i(a[r]), lane));
        a[r] = c2 * a[r] + sp2 * p;
    }
}

// Full RY layer. yt: 9 gates x {cc,ss,nss}. regY q0..q3 (masks 1,2,4,8),
// laneY q4..q8 (masks 1,2,4,8,16). sw0/sw1: deferred-CNOT column swaps
// on q0/q1 (verified R5 mechanism, unchanged).
__device__ __forceinline__ void apply_Y16(h2 (&a)[16], int lane,
                                          const int* __restrict__ yt,
                                          bool sw0, bool sw1)
{
    {   const int cc = yt[0], ss = yt[1], ns = yt[2];
        regY16<1>(a, i2h(sw0 ? ns : cc), i2h(sw0 ? cc : ns),
                     i2h(sw0 ? cc : ss), i2h(sw0 ? ss : cc)); }
    {   const int cc = yt[3], ss = yt[4], ns = yt[5];
        regY16<2>(a, i2h(sw1 ? ns : cc), i2h(sw1 ? cc : ns),
                     i2h(sw1 ? cc : ss), i2h(sw1 ? ss : cc)); }
    {   regY16<4>(a, i2h(yt[6]),  i2h(yt[8]),  i2h(yt[7]),  i2h(yt[6])); }
    {   regY16<8>(a, i2h(yt[9]),  i2h(yt[11]), i2h(yt[10]), i2h(yt[9])); }
    {   laneY16<1> (a, lane, i2h(yt[12]), i2h((lane & 1)        ? yt[13] : yt[14])); }
    {   laneY16<2> (a, lane, i2h(yt[15]), i2h(((lane >> 1) & 1) ? yt[16] : yt[17])); }
    {   laneY16<4> (a, lane, i2h(yt[18]), i2h(((lane >> 2) & 1) ? yt[19] : yt[20])); }
    {   laneY16<8> (a, lane, i2h(yt[21]), i2h(((lane >> 3) & 1) ? yt[22] : yt[23])); }
    {   laneY16<16>(a, lane, i2h(yt[24]), i2h(((lane >> 4) & 1) ? yt[25] : yt[26])); }
}

// ---- Precompute (weights-only).
// ws layout (floats): [0..144) rot fp32; ints at ws+144: ytab 54 ints;
// ints at ws+208: dtab 3*512*2 ints, layout [d][r=amp&15][l5=amp>>4]{cc,ns}.
__global__ void precomp_kernel(const float* __restrict__ w, float* __restrict__ ws)
{
    const int tid = threadIdx.x;
    float* rot = ws;
    int* ytab = (int*)(ws + 144);
    int* dtab = (int*)(ws + 208);
    if (tid < 18) {
        const float phi = w[tid*3 + 0], theta = w[tid*3 + 1], omega = w[tid*3 + 2];
        const float ct = cosf(0.5f * theta), st = sinf(0.5f * theta);
        const float apo = 0.5f * (phi + omega), amo = 0.5f * (phi - omega);
        const float ca = cosf(apo), sa = sinf(apo);
        const float cm = cosf(amo), sm = sinf(amo);
        float* m = rot + tid * 8;
        m[0] =  ca * ct; m[1] = -sa * ct;   // u00
        m[2] = -cm * st; m[3] = -sm * st;   // u01
        m[4] =  cm * st; m[5] = -sm * st;   // u10
        m[6] =  ca * ct; m[7] =  sa * ct;   // u11
        h2 cc; cc.x = (_Float16)ct;  cc.y = (_Float16)ct;
        h2 ss; ss.x = (_Float16)st;  ss.y = (_Float16)st;
        h2 ns; ns.x = (_Float16)(-st); ns.y = (_Float16)(-st);
        ytab[tid*3 + 0] = h2i(cc);
        ytab[tid*3 + 1] = h2i(ss);
        ytab[tid*3 + 2] = h2i(ns);
    }
    if (tid < 192) {
        // ring1 pull-back masks (row-update rule; procedure verified vs ring2)
        const int vmask[9] = {0x1FE,0x003,0x007,0x00F,0x01F,0x03F,0x07F,0x0FF,0x1FF};
        // ring2 pull-back masks (HW-verified R4/R5)
        const int wmask[9] = {0x0AB,0x157,0x005,0x00A,0x015,0x02A,0x055,0x0AA,0x155};
        const int d = tid >> 6, ln = tid & 63;
        for (int r = 0; r < 8; ++r) {
            const int p = (ln << 3) | r;     // enumerates all 512 amp indices
            float ang = 0.f;
            for (int q = 0; q < 9; ++q) {
                if (d == 0) {            // D_A: conj(Phi_l1) through ring1
                    const float lam = -0.5f * w[(9 + q)*3 + 0];
                    ang += (__popc(p & vmask[q]) & 1) ? -lam : lam;
                } else if (d == 1) {     // D_B: conj(Phi_l0) thru ring2 + Omega_l1
                    const float lam = -0.5f * w[q*3 + 0];
                    ang += (__popc(p & wmask[q]) & 1) ? -lam : lam;
                    const float lm2 = -0.5f * w[(9 + q)*3 + 2];
                    ang += ((p >> q) & 1) ? -lm2 : lm2;
                } else {                 // D_C: conj(Phi_l1) thru ring1 + Omega_l0
                    const float lam = -0.5f * w[(9 + q)*3 + 0];
                    ang += (__popc(p & vmask[q]) & 1) ? -lam : lam;
                    const float lm2 = -0.5f * w[q*3 + 2];
                    ang += ((p >> q) & 1) ? -lm2 : lm2;
                }
            }
            const float c = cosf(ang), s = sinf(ang);
            h2 cc;  cc.x = (_Float16)c;    cc.y = (_Float16)c;
            h2 nsp; nsp.x = (_Float16)(-s); nsp.y = (_Float16)s;  // {-s,+s}
            // coalesced-read layout: [d][p&15][p>>4]
            const int idx = (d * 512 + (p & 15) * 32 + (p >> 4)) * 2;
            dtab[idx + 0] = h2i(cc);
            dtab[idx + 1] = h2i(nsp);
        }
    }
}

__global__ __launch_bounds__(PPB * 64, 6) void qconv_kernel(
    const float* __restrict__ x,      // (8, 1, 128, 128)
    const float* __restrict__ ws,     // precomp tables
    float* __restrict__ out)          // (8, 9, 63, 63)
{
    const float* rot  = ws;
    const int* ytab = (const int*)(ws + 144);
    const int* dtab = (const int*)(ws + 208);

    const int lane   = threadIdx.x & 63;
    const int wv     = threadIdx.x >> 6;
    const int lane5  = lane & 31;
    const int half   = lane >> 5;                       // 0: patch A, 1: patch B
    const int patch2 = (blockIdx.x * PPB + wv) * 2;     // wave's first patch

    // ---- Per-wave alpha/beta staging: 72 values (2 patches x 36).
    // Pass 1: lane -> value lane (patchA j=0..35 | patchB j=0..27);
    // pass 2: lanes 0-7 -> patchB j=28..35.
    __shared__ __align__(16) float abtab[PPB][2][36];
    {
        auto stage_val = [&](int h, int j) {
            const int q = j >> 2, comp = j & 3;
            const int tp   = patch2 + h;
            const int tb   = tp / N_PIX;
            const int trem = tp - tb * N_PIX;
            const int toy  = trem / OUT_HW;
            const int tox  = trem - toy * OUT_HW;
            const int qr = q / 3, qc = q - 3 * qr;
            const float ang = x[tb * 16384 + (toy * 2 + qr) * 128 + (tox * 2 + qc)];
            float s, c;
            __sincosf(0.5f * ang, &s, &c);
            const float* R = rot + 8 * q;
            float v;
            if      (comp == 0) v = c*R[0] + s*R[3];
            else if (comp == 1) v = c*R[1] - s*R[2];
            else if (comp == 2) v = c*R[4] + s*R[7];
            else                v = c*R[5] - s*R[6];
            abtab[wv][h][j] = v;
        };
        const int h1 = (lane >= 36) ? 1 : 0;
        stage_val(h1, lane - 36 * h1);
        if (lane < 8) stage_val(1, 28 + lane);
    }
    __builtin_amdgcn_wave_barrier();   // ordering fence; DS ops of one wave
                                       // execute in order (R17/R19-verified).

    // Each lane reads its half's 36 values: 9x ds_read_b128 (rows 144B,
    // 16B-aligned; two distinct addrs/wave broadcast within halves).
    float ab[36];
    {
        const float4* src = reinterpret_cast<const float4*>(&abtab[wv][half][0]);
        float4* dst = reinterpret_cast<float4*>(ab);
        #pragma unroll
        for (int j = 0; j < 9; ++j) dst[j] = src[j];
    }

    // D_A prefetch: issue before the product build (~150 VALU of cover).
    h2 dcc[16], dns[16];
    load_diag16(dcc, dns, dtab, 0 * 512, lane5);

    // ---- Product state: amp(p) = prod_q (bit_q(p) ? beta_q : alpha_q)
    // q0..q3 -> reg bits 0..3; q4..q8 -> lane5 bits 0..4.
    // NOTE: every ab[] access uses a COMPILE-TIME index; runtime selection
    // is done on values (v_cndmask), never inside the index (R19 spill bug).
    h2 a[16];
    {
        const int bit0 = lane5 & 1;              // q4 bit
        float Lr = bit0 ? ab[18] : ab[16];
        float Li = bit0 ? ab[19] : ab[17];
        #pragma unroll
        for (int q = 5; q <= 8; ++q) {
            const int bit = (lane5 >> (q - 4)) & 1;
            const float fr = bit ? ab[4*q + 2] : ab[4*q + 0];
            const float fi = bit ? ab[4*q + 3] : ab[4*q + 1];
            const float nr = Lr*fr - Li*fi;
            const float ni = Lr*fi + Li*fr;
            Lr = nr; Li = ni;
        }
        float c01r[4], c01i[4], c23r[4], c23i[4];
        #pragma unroll
        for (int j = 0; j < 4; ++j) {
            const float f0r = (j & 1) ? ab[2]  : ab[0];
            const float f0i = (j & 1) ? ab[3]  : ab[1];
            const float f1r = (j & 2) ? ab[6]  : ab[4];
            const float f1i = (j & 2) ? ab[7]  : ab[5];
            c01r[j] = f0r*f1r - f0i*f1i;
            c01i[j] = f0r*f1i + f0i*f1r;
            const float g2r = (j & 1) ? ab[10] : ab[8];
            const float g2i = (j & 1) ? ab[11] : ab[9];
            const float g3r = (j & 2) ? ab[14] : ab[12];
            const float g3i = (j & 2) ? ab[15] : ab[13];
            c23r[j] = g2r*g3r - g2i*g3i;
            c23i[j] = g2r*g3i + g2i*g3r;
        }
        float hlr[4], hli[4];
        #pragma unroll
        for (int j = 0; j < 4; ++j) {
            hlr[j] = c01r[j]*Lr - c01i[j]*Li;
            hli[j] = c01r[j]*Li + c01i[j]*Lr;
        }
        #pragma unroll
        for (int r = 0; r < 16; ++r) {
            const float fr = hlr[r & 3]*c23r[r >> 2] - hli[r & 3]*c23i[r >> 2];
            const float fi = hlr[r & 3]*c23i[r >> 2] + hli[r & 3]*c23r[r >> 2];
            a[r] = __builtin_bit_cast(h2, __builtin_amdgcn_cvt_pkrtz(fr, fi));
        }
    }

    const bool q7b = ((lane >> 3) & 1) != 0;    // amp bit 7 (qubit 7)
    const bool q8b = ((lane >> 4) & 1) != 0;    // amp bit 8 (qubit 8)

    // U = Y1 R1 D_C Y0 R2 D_B Y1 R1 D_A |build>, measured with ring2 masks.
    apply_diag16_pre(a, dcc, dns);                    // D_A
    load_diag16(dcc, dns, dtab, 1 * 512, lane5);      // D_B prefetch
    ring1_partial16(a, lane);                         // cnot(8,0) -> Y q0 swap
    apply_Y16(a, lane, ytab + 27, q8b, false);        // Y(l=1)
    apply_diag16_pre(a, dcc, dns);                    // D_B
    load_diag16(dcc, dns, dtab, 2 * 512, lane5);      // D_C prefetch
    ring2_partial16(a, lane);                         // (7,0),(8,1) -> Y q0/q1
    apply_Y16(a, lane, ytab + 0, q7b, q8b);           // Y(l=0)
    apply_diag16_pre(a, dcc, dns);                    // D_C
    ring1_partial16(a, lane);                         // cnot(8,0) -> Y q0 swap
    apply_Y16(a, lane, ytab + 27, q8b, false);        // Y(l=1)
    // final Omega(l=1) dropped; final ring2 absorbed into the Walsh masks.

    // ---- Measurement: e_q = sum_p (-1)^{parity(p & w_q)} |amp_p|^2
    float p[16];
    #pragma unroll
    for (int r = 0; r < 16; ++r) {
#if __has_builtin(__builtin_amdgcn_fdot2)
        p[r] = __builtin_amdgcn_fdot2(__builtin_bit_cast(hw2, a[r]),
                                      __builtin_bit_cast(hw2, a[r]), 0.0f, false);
#else
        const float xr = (float)a[r].x, xi = (float)a[r].y;
        p[r] = xr*xr + xi*xi;
#endif
    }

    // 4 signed register sums over reg masks {5,7,10,11} (= wmask & 15).
    float A[8], B[8];
    #pragma unroll
    for (int j = 0; j < 8; ++j) {
        A[j] = p[2*j] + p[2*j+1];
        B[j] = p[2*j] - p[2*j+1];
    }
    float P5[4], P7[4], P10[4];
    #pragma unroll
    for (int k = 0; k < 4; ++k) {
        P5[k]  = B[2*k] + B[2*k+1];
        P7[k]  = B[2*k] - B[2*k+1];
        P10[k] = A[2*k] - A[2*k+1];
    }
    float S5  = (P5[0]  - P5[1])  + (P5[2]  - P5[3]);
    float S7  = (P7[0]  - P7[1])  + (P7[2]  - P7[3]);
    float S11 = (P7[0]  + P7[1])  - (P7[2]  + P7[3]);
    float S10 = (P10[0] + P10[1]) - (P10[2] + P10[3]);

    // ---- 4 simultaneous 32-lane Walsh-Hadamard transforms (per half).
    const int sm0 = (lane & 1) << 31;
    const int sm1 = ((lane >> 1) & 1) << 31;
    const int sm2 = ((lane >> 2) & 1) << 31;
    const int sm3 = ((lane >> 3) & 1) << 31;
    const int sm4 = ((lane >> 4) & 1) << 31;
#define WHT_STAGE(M, SM) { \
    const float qa = shfl_f<M>(S5, lane),  qb = shfl_f<M>(S7, lane); \
    const float qc = shfl_f<M>(S10, lane), qd = shfl_f<M>(S11, lane); \
    S5  = qa + __int_as_float(__float_as_int(S5)  ^ (SM)); \
    S7  = qb + __int_as_float(__float_as_int(S7)  ^ (SM)); \
    S10 = qc + __int_as_float(__float_as_int(S10) ^ (SM)); \
    S11 = qd + __int_as_float(__float_as_int(S11) ^ (SM)); }
    WHT_STAGE(1,  sm0)
    WHT_STAGE(2,  sm1)
    WHT_STAGE(4,  sm2)
    WHT_STAGE(8,  sm3)
    WHT_STAGE(16, sm4)
#undef WHT_STAGE

    // ---- Gather (per half; lane5 positions = wmask >> 4):
    // S5: e2@0, e4@1, e6@5, e8@0x15 | S10: e3@0, e5@2, e7@0xA
    // S11: e0@0xA | S7: e1@0x15
    const int patch = patch2 + half;
    const int b   = patch / N_PIX;
    const int rem = patch - b * N_PIX;
    const int oy  = rem / OUT_HW;
    const int ox  = rem - oy * OUT_HW;
    const int base = b * 9;
    const int pix  = oy * OUT_HW + ox;

    if (lane5 == 0x00) {
        out[(base + 2) * N_PIX + pix] = S5;
        out[(base + 3) * N_PIX + pix] = S10;
    }
    if (lane5 == 0x01) out[(base + 4) * N_PIX + pix] = S5;
    if (lane5 == 0x02) out[(base + 5) * N_PIX + pix] = S10;
    if (lane5 == 0x05) out[(base + 6) * N_PIX + pix] = S5;
    if (lane5 == 0x0A) {
        out[(base + 7) * N_PIX + pix] = S10;
        out[(base + 0) * N_PIX + pix] = S11;
    }
    if (lane5 == 0x15) {
        out[(base + 8) * N_PIX + pix] = S5;
        out[(base + 1) * N_PIX + pix] = S7;
    }
}

} // anonymous namespace

extern "C" void kernel_launch(void* const* d_in, const int* in_sizes, int n_in,
                              void* d_out, int out_size, void* d_ws, size_t ws_size,
                              hipStream_t stream)
{
    const float* x = (const float*)d_in[0];   // (8,1,128,128) float32
    const float* w = (const float*)d_in[1];   // (2,9,3) float32
    float* ws = (float*)d_ws;                 // ~3.3k floats scratch
    float* out = (float*)d_out;               // (8,9,63,63) float32

    precomp_kernel<<<1, 256, 0, stream>>>(w, ws);
    qconv_kernel<<<N_PATCH_TOTAL / (PPB * 2), PPB * 64, 0, stream>>>(x, ws, out);
}